// Round 15
// baseline (382.701 us; speedup 1.0000x reference)
//
#include <hip/hip_runtime.h>

#define SEQ_LEN 2048
#define BATCH   512
#define HIDDEN  25

typedef int v2i __attribute__((ext_vector_type(2)));
typedef _Float16 h2_t __attribute__((ext_vector_type(2)));

__device__ __forceinline__ float fast_rcp(float v) { return __builtin_amdgcn_rcpf(v); }

// D = a.lo*b.lo + a.hi*b.hi + c, f16 multiply / f32 accumulate
__device__ __forceinline__ float fdot2i(int a, int b, float c) {
#if __has_builtin(__builtin_amdgcn_fdot2)
    return __builtin_amdgcn_fdot2(__builtin_bit_cast(h2_t, a), __builtin_bit_cast(h2_t, b), c, false);
#else
    float d;
    asm("v_dot2_f32_f16 %0, %1, %2, %3" : "=v"(d) : "v"(a), "v"(b), "v"(c));
    return d;
#endif
}

// Pade(5,4) tanh with exact integer coefficients:
//   tanh(x) ~= x*(945+105u+u^2)/(945+420u+15u^2), u=x^2  (scaled by 1/15)
// Input clamped to [-4,4] (inline-const med3), output to [-1,1] so sigmoids
// stay <=1 (keeps the f-gate non-expansive). Max |err| ~1.1e-3 (x~3.5).
// Replaces exp2->rcp (two serial trans) with poly->rcp (one trans).
__device__ __forceinline__ float tanh_pade(float y) {
    const float x   = __builtin_amdgcn_fmed3f(y, -4.0f, 4.0f);
    const float u   = x * x;
    const float d0  = fmaf(u, 28.0f, 63.0f);
    const float den = fmaf(u, u, d0);            // u^2 + 28u + 63
    const float p   = fmaf(u, 7.0f, 63.0f);
    const float u15 = u * 0.06666666667f;        // u/15
    const float num = fmaf(u15, u, p);           // 63 + 7u + u^2/15
    const float T   = (x * num) * fast_rcp(den);
    return __builtin_amdgcn_fmed3f(T, -1.0f, 1.0f);
}

// One wave per batch element. j-PAIR layout (R13, passing):
//   lane 2j   (j=0..24): rows j      (i, sigmoid) and 50+j (g, tanh)
//   lane 2j+1 (j=0..24): rows 25+j   (f, sigmoid) and 75+j (o, sigmoid);
//                        owns c_j, h_j  (natural scale now — no log2e folding)
// i*g crosses even->odd via mov_dpp row_shr:1 (0x111). h-pack via quad_perm;
// 13 readlanes broadcast from lanes 4m+1.
// R14 delta: ALL activations via tanh_pade (sigma(z)=0.5+0.5*tanh(z/2), fold
// 0.5 into weights) — removes the two serial exp2 quanta from the chain.
__global__ __launch_bounds__(64)
__attribute__((amdgpu_waves_per_eu(1, 1)))
void lstm_kernel(
    const float* __restrict__ x,
    const float* __restrict__ W_ih,
    const float* __restrict__ W_hh,
    const float* __restrict__ b_ih,
    const float* __restrict__ b_hh,
    const float* __restrict__ W_lin,
    const float* __restrict__ b_lin,
    float* __restrict__ out)
{
    const int lane = threadIdx.x;
    const int b    = blockIdx.x;

    __shared__ float pp[64][29];   // deferred output partials; 29 coprime w/ 32 banks

    const bool odd = (lane & 1);
    const int  j   = lane >> 1;                    // hidden index of this pair
    const int  jj  = (j < HIDDEN) ? j : 0;         // clamp idle lanes 50..63
    const bool hv  = (j < HIDDEN);

    const int r1 = odd ? (HIDDEN + jj) : jj;                     // f : i (sigmoid)
    const int r2 = odd ? (3 * HIDDEN + jj) : (2 * HIDDEN + jj);  // o : g

    // tanh-argument pre-scales: sigma(z)=0.5+0.5*tanh(0.5*z); g=tanh(zg)
    const float s1 = 0.5f;                         // i, f (sigmoid)
    const float s2 = odd ? 0.5f : 1.0f;            // o: sigmoid, g: tanh
    const float m2 = odd ? 0.5f : 1.0f;            // act2 = m2*T2 + d2
    const float d2 = odd ? 0.5f : 0.0f;

    // fold scales into weights, pad k=25 with 0, pack to f16 pairs
    float w1[26], w2[26];
    #pragma unroll
    for (int k = 0; k < HIDDEN; ++k) {
        w1[k] = W_hh[r1 * HIDDEN + k] * s1;
        w2[k] = W_hh[r2 * HIDDEN + k] * s2;
    }
    w1[25] = 0.0f; w2[25] = 0.0f;
    int W1p[13], W2p[13];
    #pragma unroll
    for (int m = 0; m < 13; ++m) {
        W1p[m] = __builtin_bit_cast(int, __builtin_amdgcn_cvt_pkrtz(w1[2*m], w1[2*m+1]));
        W2p[m] = __builtin_bit_cast(int, __builtin_amdgcn_cvt_pkrtz(w2[2*m], w2[2*m+1]));
    }
    float bias1 = (b_ih[r1] + b_hh[r1]) * s1;
    float bias2 = (b_ih[r2] + b_hh[r2]) * s2;
    float wi1   = W_ih[r1] * s1;
    float wi2   = W_ih[r2] * s2;

    // pin loop-invariants into VGPRs (defeat remat/spill)
    #pragma unroll
    for (int m = 0; m < 13; ++m) {
        asm volatile("" : "+v"(W1p[m]));
        asm volatile("" : "+v"(W2p[m]));
    }
    asm volatile("" : "+v"(bias1), "+v"(bias2), "+v"(wi1), "+v"(wi2));

    const float wlin  = (odd && hv) ? W_lin[jj] : 0.0f;
    const float blin  = b_lin[0];
    const int   pcol  = (odd && hv) ? jj : 26;     // inactive lanes -> unused col

    float cs = 0.0f;   // c (natural scale; real on odd lanes)
    float vh = 0.0f;   // h (real on odd lanes)

    const float* xb = x + b;
    float xv = xb[(size_t)lane * BATCH];           // x[t=lane][b], staggered prefetch

    #pragma unroll 1
    for (int tb = 0; tb < SEQ_LEN; tb += 64) {
        float xv_next = 0.0f;
        if (tb + 64 < SEQ_LEN) xv_next = xb[(size_t)(tb + 64 + lane) * BATCH];

        #pragma unroll 4
        for (int tt = 0; tt < 64; ++tt) {
            // pack {h_2m, h_2m+1}: lane 4m+1 pairs own vh with quad lane 3's vh
            const int nb  = __builtin_amdgcn_mov_dpp(__float_as_int(vh), 0xFF, 0xF, 0xF, true); // quad_perm[3,3,3,3]
            const int hpk = __builtin_bit_cast(int,
                __builtin_amdgcn_cvt_pkrtz(vh, __int_as_float(nb)));

            // broadcast 25 h values as 13 packed words from lanes 4m+1
            int hw[13];
            #pragma unroll
            for (int m = 0; m < 13; ++m)
                hw[m] = __builtin_amdgcn_readlane(hpk, 4 * m + 1);

            const float xt = __int_as_float(__builtin_amdgcn_readlane(__float_as_int(xv), tt));

            // 3 accumulator chains per gate row (depth 5/5/3)
            float a1 = fmaf(xt, wi1, bias1);
            float a2 = fmaf(xt, wi2, bias2);
            float p1 = 0.0f, q1 = 0.0f;
            float p2 = 0.0f, q2 = 0.0f;
            #pragma unroll
            for (int m = 0; m < 5; ++m) {
                a1 = fdot2i(W1p[m], hw[m], a1);
                a2 = fdot2i(W2p[m], hw[m], a2);
            }
            #pragma unroll
            for (int m = 5; m < 10; ++m) {
                p1 = fdot2i(W1p[m], hw[m], p1);
                p2 = fdot2i(W2p[m], hw[m], p2);
            }
            #pragma unroll
            for (int m = 10; m < 13; ++m) {
                q1 = fdot2i(W1p[m], hw[m], q1);
                q2 = fdot2i(W2p[m], hw[m], q2);
            }
            a1 = (a1 + p1) + q1;
            a2 = (a2 + p2) + q2;

            // activations via Pade tanh (one rcp each, no exp2)
            const float T1   = tanh_pade(a1);
            const float T2   = tanh_pade(a2);
            const float R1   = fmaf(T1, 0.5f, 0.5f);   // i (even) / f (odd)
            const float act2 = fmaf(T2, m2, d2);       // g (even) / o (odd)

            const float igs = R1 * act2;               // i*g on even lanes
            // odd lane 2j+1 receives even lane 2j's igs: row_shr:1 = 0x111
            const float igx = __int_as_float(
                __builtin_amdgcn_mov_dpp(__float_as_int(igs), 0x111, 0xF, 0xF, true));

            cs = fmaf(R1, cs, igx);                    // c = f*c + i*g  (odd)
            const float T3 = tanh_pade(cs);            // tanh(c)
            vh = act2 * T3;                            // h = o*tanh(c)  (odd)

            pp[tt][pcol] = vh * wlin;                  // deferred output partial
        }
        // single-wave block: same-wave LDS ops are in program order -> no barrier
        float s = blin;
        #pragma unroll
        for (int k = 0; k < HIDDEN; ++k) s += pp[lane][k];
        out[(size_t)(tb + lane) * BATCH + b] = s;

        xv = xv_next;
    }
}

extern "C" void kernel_launch(void* const* d_in, const int* in_sizes, int n_in,
                              void* d_out, int out_size, void* d_ws, size_t ws_size,
                              hipStream_t stream) {
    const float* x     = (const float*)d_in[0];
    const float* W_ih  = (const float*)d_in[1];
    const float* W_hh  = (const float*)d_in[2];
    const float* b_ih  = (const float*)d_in[3];
    const float* b_hh  = (const float*)d_in[4];
    const float* W_lin = (const float*)d_in[5];
    const float* b_lin = (const float*)d_in[6];
    float* outp = (float*)d_out;

    hipLaunchKernelGGL(lstm_kernel, dim3(BATCH), dim3(64), 0, stream,
                       x, W_ih, W_hh, b_ih, b_hh, W_lin, b_lin, outp);
}

// Round 16
// 324.914 us; speedup vs baseline: 1.1779x; 1.1779x over previous
//
#include <hip/hip_runtime.h>

#define SEQ_LEN 2048
#define BATCH   512
#define HIDDEN  25

typedef int v2i __attribute__((ext_vector_type(2)));
typedef _Float16 h2_t __attribute__((ext_vector_type(2)));

__device__ __forceinline__ float fast_rcp(float v)  { return __builtin_amdgcn_rcpf(v); }
__device__ __forceinline__ float fast_exp2(float v) { return __builtin_amdgcn_exp2f(v); }

// D = a.lo*b.lo + a.hi*b.hi + c, f16 multiply / f32 accumulate
__device__ __forceinline__ float fdot2i(int a, int b, float c) {
#if __has_builtin(__builtin_amdgcn_fdot2)
    return __builtin_amdgcn_fdot2(__builtin_bit_cast(h2_t, a), __builtin_bit_cast(h2_t, b), c, false);
#else
    float d;
    asm("v_dot2_f32_f16 %0, %1, %2, %3" : "=v"(d) : "v"(a), "v"(b), "v"(c));
    return d;
#endif
}

// One wave per batch element. j-PAIR layout (R13 — session best, 325us):
//   lane 2j   (j=0..24): rows j      (i, sigmoid) and 50+j (g, tanh)
//   lane 2j+1 (j=0..24): rows 25+j   (f, sigmoid) and 75+j (o, sigmoid);
//                        owns c_j, h_j
// i*g crosses even->odd via mov_dpp row_shr:1 (0x111): lane i receives lane
// i-1's value. h-pack: lane 4m+1 packs {own h_2m, quad-lane-3's h_2m+1} via
// quad_perm; 13 readlanes broadcast from lanes 4m+1. Lanes 50..63 idle.
// Session findings baked in: readlane broadcast beats bpermute (+129cy) and
// LDS exchange (+47cy); gate scales folded into f16 weights; c kept as
// c' = -2log2e*c; parallel (not merged) gate rcps; 5/5/3 dot chains;
// waves_per_eu(1,1)+asm pins for register-resident weights; no barriers
// (single-wave block, same-wave LDS is in program order).
__global__ __launch_bounds__(64)
__attribute__((amdgpu_waves_per_eu(1, 1)))
void lstm_kernel(
    const float* __restrict__ x,
    const float* __restrict__ W_ih,
    const float* __restrict__ W_hh,
    const float* __restrict__ b_ih,
    const float* __restrict__ b_hh,
    const float* __restrict__ W_lin,
    const float* __restrict__ b_lin,
    float* __restrict__ out)
{
    const int lane = threadIdx.x;
    const int b    = blockIdx.x;

    __shared__ float pp[64][29];   // deferred output partials; 29 coprime w/ 32 banks

    const bool odd = (lane & 1);
    const int  j   = lane >> 1;                    // hidden index of this pair
    const int  jj  = (j < HIDDEN) ? j : 0;         // clamp idle lanes 50..63
    const bool hv  = (j < HIDDEN);

    const int r1 = odd ? (HIDDEN + jj) : jj;                     // f : i (sigmoid)
    const int r2 = odd ? (3 * HIDDEN + jj) : (2 * HIDDEN + jj);  // o : g

    const float LOG2E = 1.4426950408889634f;
    const float s1 = -LOG2E;                         // sigmoid pre-scale
    const float s2 = odd ? -LOG2E : (-2.0f * LOG2E); // o: sigmoid, g: tanh(=sig(2x))

    // fold scales into weights, pad k=25 with 0, pack to f16 pairs
    float w1[26], w2[26];
    #pragma unroll
    for (int k = 0; k < HIDDEN; ++k) {
        w1[k] = W_hh[r1 * HIDDEN + k] * s1;
        w2[k] = W_hh[r2 * HIDDEN + k] * s2;
    }
    w1[25] = 0.0f; w2[25] = 0.0f;
    int W1p[13], W2p[13];
    #pragma unroll
    for (int m = 0; m < 13; ++m) {
        W1p[m] = __builtin_bit_cast(int, __builtin_amdgcn_cvt_pkrtz(w1[2*m], w1[2*m+1]));
        W2p[m] = __builtin_bit_cast(int, __builtin_amdgcn_cvt_pkrtz(w2[2*m], w2[2*m+1]));
    }
    float bias1 = (b_ih[r1] + b_hh[r1]) * s1;
    float bias2 = (b_ih[r2] + b_hh[r2]) * s2;
    float wi1   = W_ih[r1] * s1;
    float wi2   = W_ih[r2] * s2;

    // pin loop-invariants into VGPRs (defeat remat/spill)
    #pragma unroll
    for (int m = 0; m < 13; ++m) {
        asm volatile("" : "+v"(W1p[m]));
        asm volatile("" : "+v"(W2p[m]));
    }
    asm volatile("" : "+v"(bias1), "+v"(bias2), "+v"(wi1), "+v"(wi2));

    const float wlin  = (odd && hv) ? W_lin[jj] : 0.0f;
    const float blin  = b_lin[0];
    const int   pcol  = (odd && hv) ? jj : 26;     // inactive lanes -> unused col

    float cs = 0.0f;   // c' = -2log2e * c   (real on odd lanes)
    float vh = 0.0f;   // h                  (real on odd lanes)

    const float* xb = x + b;
    float xv = xb[(size_t)lane * BATCH];           // x[t=lane][b], staggered prefetch

    #pragma unroll 1
    for (int tb = 0; tb < SEQ_LEN; tb += 64) {
        float xv_next = 0.0f;
        if (tb + 64 < SEQ_LEN) xv_next = xb[(size_t)(tb + 64 + lane) * BATCH];

        #pragma unroll 4
        for (int tt = 0; tt < 64; ++tt) {
            // pack {h_2m, h_2m+1}: lane 4m+1 pairs own vh with quad lane 3's vh
            const int nb  = __builtin_amdgcn_mov_dpp(__float_as_int(vh), 0xFF, 0xF, 0xF, true); // quad_perm[3,3,3,3]
            const int hpk = __builtin_bit_cast(int,
                __builtin_amdgcn_cvt_pkrtz(vh, __int_as_float(nb)));

            // broadcast 25 h values as 13 packed words from lanes 4m+1
            int hw[13];
            #pragma unroll
            for (int m = 0; m < 13; ++m)
                hw[m] = __builtin_amdgcn_readlane(hpk, 4 * m + 1);

            const float xt = __int_as_float(__builtin_amdgcn_readlane(__float_as_int(xv), tt));

            // 3 accumulator chains per gate row (depth 5/5/3)
            float a1 = fmaf(xt, wi1, bias1);
            float a2 = fmaf(xt, wi2, bias2);
            float p1 = 0.0f, q1 = 0.0f;
            float p2 = 0.0f, q2 = 0.0f;
            #pragma unroll
            for (int m = 0; m < 5; ++m) {
                a1 = fdot2i(W1p[m], hw[m], a1);
                a2 = fdot2i(W2p[m], hw[m], a2);
            }
            #pragma unroll
            for (int m = 5; m < 10; ++m) {
                p1 = fdot2i(W1p[m], hw[m], p1);
                p2 = fdot2i(W2p[m], hw[m], p2);
            }
            #pragma unroll
            for (int m = 10; m < 13; ++m) {
                q1 = fdot2i(W1p[m], hw[m], q1);
                q2 = fdot2i(W2p[m], hw[m], q2);
            }
            a1 = (a1 + p1) + q1;
            a2 = (a2 + p2) + q2;

            // parallel gate activations (rcp pair is one latency quantum)
            const float R1 = fast_rcp(1.0f + fast_exp2(a1));   // i (even) / f (odd)
            const float R2 = fast_rcp(1.0f + fast_exp2(a2));   // sig(2zg) (even) / o (odd)

            // even: igs = i * g * (-2log2e), g = 2*R2 - 1
            const float Gp  = fmaf(R2, -4.0f * LOG2E, 2.0f * LOG2E);
            const float igs = R1 * Gp;
            // odd lane 2j+1 receives even lane 2j's igs: row_shr:1 = 0x111
            const float igx = __int_as_float(
                __builtin_amdgcn_mov_dpp(__float_as_int(igs), 0x111, 0xF, 0xF, true));

            cs = fmaf(R1, cs, igx);                // c' = f*c' + (-2log2e)*i*g  (odd)
            const float R3 = fast_rcp(1.0f + fast_exp2(cs));   // sig(2c): tanh(c)=2R3-1
            const float o2 = R2 + R2;              // 2o (off critical path)
            vh = fmaf(o2, R3, -R2);                // h = o*tanh(c) = 2o*R3 - o  (odd)

            pp[tt][pcol] = vh * wlin;              // deferred output partial
        }
        // single-wave block: same-wave LDS ops are in program order -> no barrier
        float s = blin;
        #pragma unroll
        for (int k = 0; k < HIDDEN; ++k) s += pp[lane][k];
        out[(size_t)(tb + lane) * BATCH + b] = s;

        xv = xv_next;
    }
}

extern "C" void kernel_launch(void* const* d_in, const int* in_sizes, int n_in,
                              void* d_out, int out_size, void* d_ws, size_t ws_size,
                              hipStream_t stream) {
    const float* x     = (const float*)d_in[0];
    const float* W_ih  = (const float*)d_in[1];
    const float* W_hh  = (const float*)d_in[2];
    const float* b_ih  = (const float*)d_in[3];
    const float* b_hh  = (const float*)d_in[4];
    const float* W_lin = (const float*)d_in[5];
    const float* b_lin = (const float*)d_in[6];
    float* outp = (float*)d_out;

    hipLaunchKernelGGL(lstm_kernel, dim3(BATCH), dim3(64), 0, stream,
                       x, W_ih, W_hh, b_ih, b_hh, W_lin, b_lin, outp);
}